// Round 6
// baseline (137.109 us; speedup 1.0000x reference)
//
#include <hip/hip_runtime.h>

// NegativeSelection: score[i] = max(min_j ||x_i - s_j|| - 0.1, 0)
// N=16384, M=8192, D=128, fp32 in/out.
//
// R6: TWO kernels (was 3) — total-minus-gemm has been a constant ~55-60 us
// across all rounds => per-dispatch overhead. prep-A and final are gone:
//  * A converted in the gemm prologue (fp32 -> negated fp16 frags, a2
//    computed in-register from the same fp32 values).
//  * final fused into gemm: atomicMin on BIAS-shifted float bits + per-rb
//    completion counter; last slice-block writes out.
// K-loop: R1's winning LDS staging, now double-buffered with ONE barrier
// per iteration (prefetch issued right after the barrier -> next barrier's
// vmcnt(0) drain finds the loads already landed).
//
// ws: Bws fp16 [M*128] tiled [tile][k8][row][8]   (2 MB)
//     b2h f32 [M] = 0.5*|s_j|^2                    (32 KB)
//     Pmin u32 [N] biased-float bits               (64 KB)
//     cnt u32 [N/128] completion counters          (512 B)
//   total ~2.1 MB (smaller re-poison footprint too).

using half_t = _Float16;
typedef _Float16 half8 __attribute__((ext_vector_type(8)));
typedef float floatx16 __attribute__((ext_vector_type(16)));

#define TILE_ELEMS (128 * 128)
#define BIAS 160.0f

__device__ __forceinline__ void async_load16(const void* g, void* l) {
    __builtin_amdgcn_global_load_lds(
        (const __attribute__((address_space(1))) void*)g,
        (__attribute__((address_space(3))) void*)l, 16, 0, 0);
}

// Block = 64-row chunk of self (128 blocks). Converts fp32 -> fp16 tiled
// [k8][row][8] via padded-LDS transpose (both global sides coalesced),
// computes b2h, and inits Pmin (+inf bits) and cnt (0).
__global__ __launch_bounds__(256) void prep_b_kernel(
    const float* __restrict__ self, half_t* __restrict__ Bws,
    float* __restrict__ b2h, unsigned* __restrict__ Pmin,
    unsigned* __restrict__ cnt, int N)
{
    __shared__ float sm[64 * 129];
    __shared__ float part[256];
    int lb = blockIdx.x, tid = threadIdx.x;

    int g = lb * 256 + tid;                  // 32768 threads >= N
    if (g < N)   Pmin[g] = 0x7F800000u;      // +inf bits
    if (g < 128) cnt[g]  = 0u;

    const float* src = self + (size_t)lb * (64 * 128);
    int tile = lb >> 1, h = lb & 1;
    half_t* dstT = Bws + (size_t)tile * TILE_ELEMS;

    // Phase A: coalesced float4 read of the 64x128 fp32 chunk -> padded LDS.
    #pragma unroll
    for (int i = 0; i < 8; ++i) {
        int f   = i * 256 + tid;
        int row = f >> 5, c4 = f & 31;
        float4 v = ((const float4*)src)[f];
        *(float4*)&sm[row * 129 + c4 * 4] = v;
    }
    __syncthreads();

    // Phase B: chunk (k8 = i*4 + tid>>6, r = tid&63) -> fp16, coalesced 16B.
    int r = tid & 63;
    float ss = 0.f;
    #pragma unroll
    for (int i = 0; i < 4; ++i) {
        int k8 = i * 4 + (tid >> 6);
        float4 a = *(const float4*)&sm[r * 129 + k8 * 8];
        float4 b = *(const float4*)&sm[r * 129 + k8 * 8 + 4];
        half8 hv;
        hv[0] = (half_t)a.x; hv[1] = (half_t)a.y;
        hv[2] = (half_t)a.z; hv[3] = (half_t)a.w;
        hv[4] = (half_t)b.x; hv[5] = (half_t)b.y;
        hv[6] = (half_t)b.z; hv[7] = (half_t)b.w;
        *(half8*)(dstT + (size_t)(k8 * 128 + h * 64 + r) * 8) = hv;
        ss += a.x*a.x + a.y*a.y + a.z*a.z + a.w*a.w;
        ss += b.x*b.x + b.y*b.y + b.z*b.z + b.w*b.w;
    }
    part[tid] = ss;
    __syncthreads();
    if (tid < 64) {
        float s4 = part[tid] + part[tid + 64] + part[tid + 128] + part[tid + 192];
        b2h[lb * 64 + tid] = 0.5f * s4;
    }
}

// Grid (N/128, 4) = 512 blocks = 2/CU. Block = 4 waves 2x2; wave = 64r x 64c
// per 128-col tile, 16 tiles. Double-buffered LDS, ONE barrier per iter.
// acc = (b2/2 + BIAS) - dot  (A negated at convert time).
__global__ __launch_bounds__(256, 2) void min_gemm_kernel(
    const float* __restrict__ x, const half_t* __restrict__ Bws,
    const float* __restrict__ b2h, unsigned* __restrict__ Pmin,
    unsigned* __restrict__ cnt, float* __restrict__ out)
{
    __shared__ half_t Bsh[2][TILE_ELEMS];   // 2 x 32 KB
    __shared__ bool lastFlag;

    int tid  = threadIdx.x;
    int lane = tid & 63;
    int wid  = tid >> 6;
    int wr   = wid >> 1, wc = wid & 1;
    int ln31 = lane & 31, lh = lane >> 5;
    int rb = blockIdx.x, s = blockIdx.y;
    int t0 = s * 16;

    // Issue tile t0 -> buf 0 (overlaps with the A prologue below).
    {
        const half_t* Bt = Bws + (size_t)t0 * TILE_ELEMS;
        #pragma unroll
        for (int j = 0; j < 8; ++j) {
            int seg = wid * 8 + j;
            async_load16(Bt + (size_t)(seg * 64 + lane) * 8,
                         &Bsh[0][(size_t)seg * 512]);
        }
    }

    // A prologue: fp32 loads (once per block), negated fp16 frags + a2.
    const float* Ablk = x + (size_t)rb * 128 * 128;
    half8 areg[2][8];
    float a2reg[2];
    #pragma unroll
    for (int rt = 0; rt < 2; ++rt) {
        int row = wr * 64 + rt * 32 + ln31;
        float ss = 0.f;
        #pragma unroll
        for (int ki = 0; ki < 8; ++ki) {
            int k8 = ki * 2 + lh;
            const float4* p = (const float4*)(Ablk + (size_t)row * 128 + k8 * 8);
            float4 f0 = p[0], f1 = p[1];
            half8 hv;
            hv[0] = (half_t)(-f0.x); hv[1] = (half_t)(-f0.y);
            hv[2] = (half_t)(-f0.z); hv[3] = (half_t)(-f0.w);
            hv[4] = (half_t)(-f1.x); hv[5] = (half_t)(-f1.y);
            hv[6] = (half_t)(-f1.z); hv[7] = (half_t)(-f1.w);
            areg[rt][ki] = hv;
            ss += f0.x*f0.x + f0.y*f0.y + f0.z*f0.z + f0.w*f0.w;
            ss += f1.x*f1.x + f1.y*f1.y + f1.z*f1.z + f1.w*f1.w;
        }
        // this thread covered k8 = {2ki+lh}: half the k-range; partner lane
        // (lh^1, same ln31, same row) has the other half.
        a2reg[rt] = ss + __shfl_xor(ss, 32, 64);
    }

    float minacc[2][16];
    #pragma unroll
    for (int rt = 0; rt < 2; ++rt)
        #pragma unroll
        for (int r = 0; r < 16; ++r) minacc[rt][r] = 1e30f;

    for (int i = 0; i < 16; ++i) {
        int p = i & 1;
        __syncthreads();   // buf[p] ready; prior reads of buf[p^1] done
        if (i + 1 < 16) {  // prefetch next tile into the buffer just freed
            const half_t* Bt = Bws + (size_t)(t0 + i + 1) * TILE_ELEMS;
            #pragma unroll
            for (int j = 0; j < 8; ++j) {
                int seg = wid * 8 + j;
                async_load16(Bt + (size_t)(seg * 64 + lane) * 8,
                             &Bsh[p ^ 1][(size_t)seg * 512]);
            }
        }

        int gcol = (t0 + i) * 128 + wc * 64 + ln31;
        float b2v0 = b2h[gcol]      + BIAS;
        float b2v1 = b2h[gcol + 32] + BIAS;

        floatx16 acc00, acc01, acc10, acc11;
        #pragma unroll
        for (int r = 0; r < 16; ++r) {
            acc00[r] = b2v0; acc01[r] = b2v1;
            acc10[r] = b2v0; acc11[r] = b2v1;
        }

        #pragma unroll
        for (int ki = 0; ki < 8; ++ki) {
            int k8 = ki * 2 + lh;
            half8 bf0 = *(const half8*)&Bsh[p][(size_t)(k8 * 128 + wc * 64 + ln31) * 8];
            half8 bf1 = *(const half8*)&Bsh[p][(size_t)(k8 * 128 + wc * 64 + 32 + ln31) * 8];
            acc00 = __builtin_amdgcn_mfma_f32_32x32x16_f16(areg[0][ki], bf0, acc00, 0, 0, 0);
            acc01 = __builtin_amdgcn_mfma_f32_32x32x16_f16(areg[0][ki], bf1, acc01, 0, 0, 0);
            acc10 = __builtin_amdgcn_mfma_f32_32x32x16_f16(areg[1][ki], bf0, acc10, 0, 0, 0);
            acc11 = __builtin_amdgcn_mfma_f32_32x32x16_f16(areg[1][ki], bf1, acc11, 0, 0, 0);
        }

        #pragma unroll
        for (int r = 0; r < 16; ++r) {
            minacc[0][r] = fminf(minacc[0][r], fminf(acc00[r], acc01[r]));
            minacc[1][r] = fminf(minacc[1][r], fminf(acc10[r], acc11[r]));
        }
    }

    // Lane-min over the 32 column-lanes, then device atomicMin (values are
    // BIAS-shifted positive => float bits are uint-ordered).
    // C/D row = (r&3) + 8*(r>>2) + 4*lh.
    #pragma unroll
    for (int rt = 0; rt < 2; ++rt)
        #pragma unroll
        for (int r = 0; r < 16; ++r) {
            float v = minacc[rt][r];
            #pragma unroll
            for (int m = 1; m < 32; m <<= 1)
                v = fminf(v, __shfl_xor(v, m, 64));
            if (ln31 == 0) {
                int grow = rb * 128 + wr * 64 + rt * 32
                         + (r & 3) + 8 * (r >> 2) + 4 * lh;
                atomicMin(&Pmin[grow], __float_as_uint(v));
            }
        }

    // Completion counter: last of the 4 slice-blocks for rb writes out.
    __threadfence();
    __syncthreads();
    if (tid == 0) lastFlag = (atomicAdd(&cnt[rb], 1u) == 3u);
    __syncthreads();
    if (!lastFlag) return;
    __threadfence();

    if (wc == 0 && lh == 0) {   // one lane per row (wc/lh duplicates skip)
        #pragma unroll
        for (int rt = 0; rt < 2; ++rt) {
            int grow = rb * 128 + wr * 64 + rt * 32 + ln31;
            unsigned pb = __hip_atomic_load(&Pmin[grow], __ATOMIC_RELAXED,
                                            __HIP_MEMORY_SCOPE_AGENT);
            float pm = __uint_as_float(pb) - BIAS;
            float d2 = a2reg[rt] + 2.f * pm;
            out[grow] = fmaxf(sqrtf(fmaxf(d2, 0.f)) - 0.1f, 0.f);
        }
    }
}

extern "C" void kernel_launch(void* const* d_in, const int* in_sizes, int n_in,
                              void* d_out, int out_size, void* d_ws, size_t ws_size,
                              hipStream_t stream)
{
    const float* x    = (const float*)d_in[0];
    const float* self = (const float*)d_in[1];
    float* out        = (float*)d_out;

    int N = in_sizes[0] / 128;   // 16384
    int M = in_sizes[1] / 128;   // 8192

    char* w        = (char*)d_ws;
    half_t* Bws    = (half_t*)w;
    float*  b2h    = (float*)(w + (size_t)M * 128 * 2);
    unsigned* Pmin = (unsigned*)(b2h + M);
    unsigned* cnt  = Pmin + N;
    // ws: 2 MB + 32 KB + 64 KB + 512 B ≈ 2.1 MB

    prep_b_kernel<<<M / 64, 256, 0, stream>>>(self, Bws, b2h, Pmin, cnt, N);

    dim3 grid(N / 128, 4);       // 512 blocks = 2/CU
    min_gemm_kernel<<<grid, 256, 0, stream>>>(x, Bws, b2h, Pmin, cnt, out);
}